// Round 1
// baseline (224.238 us; speedup 1.0000x reference)
//
#include <hip/hip_runtime.h>
#include <math.h>

static constexpr int kM = 80;
static constexpr int kT = 4000;
static constexpr int kB = 64;
static constexpr int kLow = kM / 3;              // 26
static constexpr int kHighStart = 2 * kM / 3;    // 53
static constexpr int kHighCount = kM - kHighStart; // 27
#define EPSF 1e-6f

// ---------------- Kernel A: gate[b,t] from cross-channel reductions ----------
__global__ __launch_bounds__(256) void gate_kernel(
    const float* __restrict__ mel,
    const float* __restrict__ gate_temp,
    float* __restrict__ gate)
{
    const int b = blockIdx.y;
    const int t0 = (blockIdx.x * 256 + threadIdx.x) * 4;
    if (t0 >= kT) return;
    const float* base = mel + (size_t)b * kM * kT + t0;

    float slog[4]  = {0.f, 0.f, 0.f, 0.f};
    float ssum[4]  = {0.f, 0.f, 0.f, 0.f};
    float slow[4]  = {0.f, 0.f, 0.f, 0.f};
    float shigh[4] = {0.f, 0.f, 0.f, 0.f};

    #pragma unroll 4
    for (int m = 0; m < kM; ++m) {
        const float4 v = *reinterpret_cast<const float4*>(base + (size_t)m * kT);
        const float vv[4] = {v.x, v.y, v.z, v.w};
        #pragma unroll
        for (int q = 0; q < 4; ++q) {
            slog[q] += __logf(vv[q] + 1e-8f);
            ssum[q] += vv[q];
        }
        if (m < kLow) {
            #pragma unroll
            for (int q = 0; q < 4; ++q) slow[q] += vv[q];
        }
        if (m >= kHighStart) {
            #pragma unroll
            for (int q = 0; q < 4; ++q) shigh[q] += vv[q];
        }
    }

    const float gt = gate_temp[0];
    float g4[4];
    #pragma unroll
    for (int q = 0; q < 4; ++q) {
        const float geo   = __expf(slog[q] * (1.0f / kM));
        const float arith = ssum[q] * (1.0f / kM) + 1e-8f;
        float sf = geo / arith;
        sf = fminf(fmaxf(sf, 0.0f), 1.0f);
        const float low  = slow[q]  * (1.0f / kLow);
        const float high = shigh[q] * (1.0f / kHighCount);
        float tilt = low / (low + high + 1e-8f);
        tilt = fminf(fmaxf(tilt, 0.0f), 1.0f);
        const float sfa = sf + (1.0f - sf) * fmaxf(tilt - 0.6f, 0.0f);
        g4[q] = 1.0f / (1.0f + __expf(-gt * (sfa - 0.5f)));
    }
    float4 o; o.x = g4[0]; o.y = g4[1]; o.z = g4[2]; o.w = g4[3];
    *reinterpret_cast<float4*>(gate + (size_t)b * kT + t0) = o;
}

// ---------------- Kernel B: dual PCEN scan + gated blend ---------------------
// One block per (b,m) row. 256 threads x 16 elements = 4096 >= 4000.
// IIR sm[t] = a*sm[t-1] + s*x[t], carry sm[-1] = x[0]  (gives sm[0]=x[0]).
// Chunked affine scan: chunk transform v -> A*v + B, composed via
// Hillis-Steele shuffle scan within a wave + LDS across the 4 waves.
__global__ __launch_bounds__(256) void pcen_kernel(
    const float* __restrict__ mel,
    const float* __restrict__ ls_ns, const float* __restrict__ la_ns,
    const float* __restrict__ ld_ns, const float* __restrict__ lr_ns,
    const float* __restrict__ ls_st, const float* __restrict__ la_st,
    const float* __restrict__ ld_st, const float* __restrict__ lr_st,
    const float* __restrict__ gate,
    float* __restrict__ out)
{
    const int m = blockIdx.x;
    const int b = blockIdx.y;

    // per-channel params (uniform across block; one-time precise expf)
    const float s_ns     = fminf(fmaxf(1.0f / (1.0f + expf(-ls_ns[m])), 0.05f), 0.3f);
    const float alpha_ns = fminf(fmaxf(1.0f / (1.0f + expf(-la_ns[m])), 0.9f), 0.999f);
    const float delta_ns = fminf(fmaxf(expf(ld_ns[m]), 0.5f), 5.0f);
    const float r_ns     = fminf(fmaxf(1.0f / (1.0f + expf(-lr_ns[m])), 0.05f), 0.25f);
    const float s_st     = fminf(fmaxf(1.0f / (1.0f + expf(-ls_st[m])), 0.05f), 0.3f);
    const float alpha_st = fminf(fmaxf(1.0f / (1.0f + expf(-la_st[m])), 0.9f), 0.999f);
    const float delta_st = fminf(fmaxf(expf(ld_st[m]), 0.001f), 0.1f);
    const float r_st     = fminf(fmaxf(1.0f / (1.0f + expf(-lr_st[m])), 0.05f), 0.25f);
    const float dr_ns = powf(delta_ns, r_ns);
    const float dr_st = powf(delta_st, r_st);
    const float a_ns = 1.0f - s_ns;
    const float a_st = 1.0f - s_st;

    const size_t rowoff = ((size_t)b * kM + m) * kT;
    const float* row = mel + rowoff;

    const int tid = threadIdx.x;
    const int t0  = tid * 16;
    const bool valid = (t0 < kT);   // tids 250..255 are identity lanes

    float x[16];
    if (valid) {
        const float4* p = reinterpret_cast<const float4*>(row + t0);
        #pragma unroll
        for (int q = 0; q < 4; ++q) {
            const float4 v = p[q];
            x[4*q+0] = v.x; x[4*q+1] = v.y; x[4*q+2] = v.z; x[4*q+3] = v.w;
        }
    } else {
        #pragma unroll
        for (int k = 0; k < 16; ++k) x[k] = 0.0f;
    }

    __shared__ float sv0;
    if (tid == 0) sv0 = x[0];

    // local chunk transform: run recurrence from 0 -> B; A = a^16
    float An = 1.0f, Bn = 0.0f, As = 1.0f, Bs = 0.0f;
    if (valid) {
        #pragma unroll
        for (int k = 0; k < 16; ++k) {
            Bn = a_ns * Bn + s_ns * x[k];
            Bs = a_st * Bs + s_st * x[k];
        }
        const float a2n = a_ns*a_ns, a4n = a2n*a2n, a8n = a4n*a4n;
        const float a2s = a_st*a_st, a4s = a2s*a2s, a8s = a4s*a4s;
        An = a8n * a8n;
        As = a8s * a8s;
    }

    const int lane = tid & 63;
    const int wid  = tid >> 6;

    // inclusive Hillis-Steele composition scan within wave
    #pragma unroll
    for (int d = 1; d < 64; d <<= 1) {
        const float qAn = __shfl_up(An, d);
        const float qBn = __shfl_up(Bn, d);
        const float qAs = __shfl_up(As, d);
        const float qBs = __shfl_up(Bs, d);
        if (lane >= d) {
            Bn = An * qBn + Bn; An = An * qAn;
            Bs = As * qBs + Bs; As = As * qAs;
        }
    }

    __shared__ float wAn[4], wBn[4], wAs[4], wBs[4];
    if (lane == 63) { wAn[wid] = An; wBn[wid] = Bn; wAs[wid] = As; wBs[wid] = Bs; }
    __syncthreads();

    // exclusive within wave
    float eAn = __shfl_up(An, 1);
    float eBn = __shfl_up(Bn, 1);
    float eAs = __shfl_up(As, 1);
    float eBs = __shfl_up(Bs, 1);
    if (lane == 0) { eAn = 1.0f; eBn = 0.0f; eAs = 1.0f; eBs = 0.0f; }

    // composition of all preceding waves (at most 3 iterations)
    float pAn = 1.0f, pBn = 0.0f, pAs = 1.0f, pBs = 0.0f;
    for (int j = 0; j < wid; ++j) {
        pBn = wAn[j] * pBn + wBn[j]; pAn = wAn[j] * pAn;
        pBs = wAs[j] * pBs + wBs[j]; pAs = wAs[j] * pAs;
    }

    // carry into this chunk: sm value just before t0
    const float v0 = sv0;
    float smn = eAn * (pAn * v0 + pBn) + eBn;
    float sms = eAs * (pAs * v0 + pBs) + eBs;

    if (valid) {
        float gv[16];
        const float4* gp = reinterpret_cast<const float4*>(gate + (size_t)b * kT + t0);
        #pragma unroll
        for (int q = 0; q < 4; ++q) {
            const float4 v = gp[q];
            gv[4*q+0] = v.x; gv[4*q+1] = v.y; gv[4*q+2] = v.z; gv[4*q+3] = v.w;
        }

        float res[16];
        #pragma unroll
        for (int k = 0; k < 16; ++k) {
            const float xv = x[k];
            smn = a_ns * smn + s_ns * xv;
            sms = a_st * sms + s_st * xv;
            const float gain_n = __expf(-alpha_ns * __logf(smn + EPSF));
            const float on = __expf(r_ns * __logf(fmaf(xv, gain_n, delta_ns))) - dr_ns;
            const float gain_s = __expf(-alpha_st * __logf(sms + EPSF));
            const float os = __expf(r_st * __logf(fmaf(xv, gain_s, delta_st))) - dr_st;
            const float g = gv[k];
            res[k] = fmaf(g, os - on, on);   // g*os + (1-g)*on
        }

        float4* op = reinterpret_cast<float4*>(out + rowoff + t0);
        #pragma unroll
        for (int q = 0; q < 4; ++q) {
            float4 v;
            v.x = res[4*q+0]; v.y = res[4*q+1]; v.z = res[4*q+2]; v.w = res[4*q+3];
            op[q] = v;
        }
    }
}

extern "C" void kernel_launch(void* const* d_in, const int* in_sizes, int n_in,
                              void* d_out, int out_size, void* d_ws, size_t ws_size,
                              hipStream_t stream)
{
    const float* mel       = (const float*)d_in[0];
    const float* ls_ns     = (const float*)d_in[1];
    const float* la_ns     = (const float*)d_in[2];
    const float* ld_ns     = (const float*)d_in[3];
    const float* lr_ns     = (const float*)d_in[4];
    const float* ls_st     = (const float*)d_in[5];
    const float* la_st     = (const float*)d_in[6];
    const float* ld_st     = (const float*)d_in[7];
    const float* lr_st     = (const float*)d_in[8];
    const float* gate_temp = (const float*)d_in[9];
    float* out  = (float*)d_out;
    float* gate = (float*)d_ws;   // kB*kT floats = 1.02 MB scratch

    dim3 gA((kT + 1023) / 1024, kB);     // 4 x 64 blocks, 256 thr, 4 cols/thr
    gate_kernel<<<gA, 256, 0, stream>>>(mel, gate_temp, gate);

    dim3 gB(kM, kB);                     // 5120 blocks, one (b,m) row each
    pcen_kernel<<<gB, 256, 0, stream>>>(mel, ls_ns, la_ns, ld_ns, lr_ns,
                                        ls_st, la_st, ld_st, lr_st, gate, out);
}